// Round 13
// baseline (244.646 us; speedup 1.0000x reference)
//
#include <hip/hip_runtime.h>
#include <math.h>

#define D   128
#define DA  8
#define DE  64
#define DMH 192

typedef unsigned short u16;
typedef unsigned int   u32;
typedef __attribute__((ext_vector_type(8))) short bfrag;   // 8 bf16 = 4 VGPRs
typedef __attribute__((ext_vector_type(4))) float facc;    // MFMA C/D

__device__ inline u16 f2bf(float v) {
    unsigned u = __float_as_uint(v);
    return (u16)((u + 0x7fffu + ((u >> 16) & 1u)) >> 16);   // RNE
}
__device__ inline float bf2f(u16 v) { return __uint_as_float((u32)v << 16); }
__device__ inline u32 pack2(float a, float b) {
    return (u32)f2bf(a) | ((u32)f2bf(b) << 16);
}
__device__ inline bfrag bzero() {
    bfrag r;
#pragma unroll
    for (int i = 0; i < 8; ++i) r[i] = 0;
    return r;
}
// swizzled LDS fragment readers (row-XOR banks)
__device__ inline bfrag afrag16(const u16* wlds, int row, int kb) {   // stride 256B
    int off = row * 256 + (((kb >> 3) * 16) ^ ((row & 7) << 4));
    return *(const bfrag*)((const char*)wlds + off);
}
__device__ inline bfrag zfrag16(const u16* wlds, int row, int kb) {   // stride 384B
    int off = row * 384 + (((kb >> 3) * 16) ^ ((row & 7) << 4));
    return *(const bfrag*)((const char*)wlds + off);
}
__device__ inline void st_swz(u16* wlds, int row, int col, int stride, float v) {
    *(u16*)((char*)wlds + row * stride
            + ((((col >> 3) * 16) ^ ((row & 7) << 4)) + (col & 7) * 2)) = f2bf(v);
}
// T14 async-stage split helpers: issue loads early, ds_write late
__device__ inline void ldw8(bfrag* r, const u16* __restrict__ src, int t) {
#pragma unroll
    for (int i = 0; i < 8; ++i)
        r[i] = *(const bfrag*)(src + (size_t)((i << 8) + t) * 8);
}
__device__ inline void stw8(u16* __restrict__ dst, const bfrag* r, int t) {
#pragma unroll
    for (int i = 0; i < 8; ++i)
        *(bfrag*)(dst + ((i << 8) + t) * 8) = r[i];
}
__device__ inline void ldw9(bfrag* r, const u16* __restrict__ src, int t) {
#pragma unroll
    for (int i = 0; i < 9; ++i)
        r[i] = *(const bfrag*)(src + (size_t)((i * 256 + t) << 3));
}
__device__ inline void stw9(u16* __restrict__ dst, const bfrag* r, int t) {
#pragma unroll
    for (int i = 0; i < 9; ++i)
        *(bfrag*)(dst + ((i * 256 + t) << 3)) = r[i];
}

// --------------------------------------------------------------- prep_all ---
// 1) weights -> bf16, repacked fragment-major: dst[((tct*nks+ks)*64+lane)*8+m]
//    = W[tct*16+(lane&15)][ks*32+(lane>>4)*8+m]  (emb stays row-major bf16)
// 2) x -> bf16   3) rowptr build
struct PrepSrc { const float* p[14]; };
__global__ __launch_bounds__(256) void prep_all(
    PrepSrc ps, u16* __restrict__ wb,
    const float* __restrict__ x, u16* __restrict__ xb, long n8,
    const int* __restrict__ row, int* __restrict__ rowptr, int E, int N)
{
    long task = (long)blockIdx.x * 256 + threadIdx.x;
    if (task < 194880) {
        int idx = (int)task;
        const int roff[13] = {0, 16384, 32768, 49152, 65536, 81920, 98304,
                              135168, 172032, 184320, 186368, 188416, 194880};
        int r = 0;
#pragma unroll
        for (int k = 1; k < 12; ++k) if (idx >= roff[k]) r = k;
        int local = idx - roff[r];
        float v;
        if (r == 11) {
            v = ps.p[13][local];                       // emb, plain
        } else {
            int K   = (r >= 6 && r <= 8) ? DMH : D;
            int nks = K >> 5;
            int m = local & 7, lane = (local >> 3) & 63;
            int l16 = lane & 15, lg = lane >> 4;
            int rest = local >> 9;
            int ks = rest % nks, tct = rest / nks;
            int rrow = tct * 16 + l16;
            int k = ks * 32 + lg * 8 + m;
            if (r == 9)       v = (rrow < 8) ? ps.p[9][rrow * D + k]
                                             : ps.p[10][(rrow - 8) * D + k];
            else if (r == 10) v = (rrow < 8) ? ps.p[11][rrow * D + k]
                                             : ps.p[12][(rrow - 8) * D + k];
            else              v = ps.p[r][(size_t)rrow * K + k];
        }
        wb[idx] = f2bf(v);
        return;
    }
    task -= 194880;
    if (task < n8) {                                    // x -> bf16
        long i = task;
        __align__(16) float buf[8];
        const float4* p = (const float4*)(x + i * 8);
        ((float4*)buf)[0] = p[0];
        ((float4*)buf)[1] = p[1];
        bfrag o;
#pragma unroll
        for (int k = 0; k < 8; ++k) o[k] = (short)f2bf(buf[k]);
        *(bfrag*)(xb + i * 8) = o;
        return;
    }
    task -= n8;
    if (task < E) {                                     // rowptr
        int e = (int)task;
        int cur  = row[e];
        int prev = (e == 0) ? -1 : row[e - 1];
        for (int r2 = prev + 1; r2 <= cur; ++r2) rowptr[r2] = e;
        if (e == E - 1)
            for (int r2 = cur + 1; r2 <= N; ++r2) rowptr[r2] = E;
    }
}

// --------------------------------------------------- ar/ac projection (L0) --
// 4 independent waves per 256-thread block
__global__ __launch_bounds__(256) void calc_arac(
    const u16* __restrict__ Xb, const u16* __restrict__ wrc,
    float* __restrict__ ar, float* __restrict__ ac, int N)
{
    const int t = threadIdx.x;
    const int w = t >> 6, l = t & 63, l16 = l & 15, lg = l >> 4;
    const long r0 = (long)blockIdx.x * 64 + w * 16;
    const long ia = r0 + l16;
    bfrag a[4];
#pragma unroll
    for (int ks = 0; ks < 4; ++ks)
        a[ks] = (ia < N) ? *(const bfrag*)(Xb + ia * D + ks * 32 + lg * 8) : bzero();
    facc acc = (facc){0, 0, 0, 0};
#pragma unroll
    for (int ks = 0; ks < 4; ++ks) {
        bfrag b = *(const bfrag*)(wrc + ((ks * 64 + l) << 3));
        acc = __builtin_amdgcn_mfma_f32_16x16x32_bf16(a[ks], b, acc, 0, 0, 0);
    }
#pragma unroll
    for (int j = 0; j < 4; ++j) {
        long i = r0 + lg * 4 + j;
        if (i < N) {
            if (l16 < 8) ar[i * DA + l16] = acc[j];
            else         ac[i * DA + (l16 - 8)] = acc[j];
        }
    }
}

// -------------------------------------------------------------- edge s ------
__global__ void edge_score(const int* __restrict__ row, const int* __restrict__ col,
                           const float* __restrict__ ar, const float* __restrict__ ac,
                           float* __restrict__ sbuf, int E)
{
    int e = blockIdx.x * 256 + threadIdx.x;
    if (e >= E) return;
    int r = row[e], c = col[e];
    float4 a0 = *(const float4*)&ar[(long)r * DA];
    float4 a1 = *(const float4*)&ar[(long)r * DA + 4];
    float4 c0 = *(const float4*)&ac[(long)c * DA];
    float4 c1 = *(const float4*)&ac[(long)c * DA + 4];
    float s = a0.x * c0.x + a0.y * c0.y + a0.z * c0.z + a0.w * c0.w
            + a1.x * c1.x + a1.y * c1.y + a1.z * c1.z + a1.w * c1.w;
    s *= 0.35355339059327373f;           // 1/sqrt(8)
    s = (s >= 0.f) ? s : 0.2f * s;       // leaky relu
    sbuf[e] = expf(s);                   // global-max shift cancels in the row norm
}

// ----------------------------------------------------------- aggregate ------
// 4 independent waves/block, one node per wave; 2 bf16 cols/lane.
// 8-deep gather pipeline + 4-deep step + predicated 0..3 remainder.
__global__ __launch_bounds__(256) void aggregate_b(
    const int* __restrict__ rowptr, const int* __restrict__ col,
    const float* __restrict__ sbuf, const u32* __restrict__ Xb2,
    u32* __restrict__ aggb2, int N)
{
    const int w = threadIdx.x >> 6, l = threadIdx.x & 63;
    const int n = blockIdx.x * 4 + w;
    if (n >= N) return;
    const int e0 = rowptr[n], e1 = rowptr[n + 1];
    float p0 = 0.f, p1 = 0.f, ds = 0.f;
    int e = e0;
    for (; e + 8 <= e1; e += 8) {
        float ss[8]; u32 uu[8];
#pragma unroll
        for (int k = 0; k < 8; ++k) {
            int c = col[e + k];
            ss[k] = sbuf[e + k];
            uu[k] = Xb2[((u32)c << 6) + l];
        }
#pragma unroll
        for (int k = 0; k < 8; ++k) {
            ds += ss[k];
            p0 += ss[k] * __uint_as_float(uu[k] << 16);
            p1 += ss[k] * __uint_as_float(uu[k] & 0xffff0000u);
        }
    }
    if (e + 4 <= e1) {
        float ss[4]; u32 uu[4];
#pragma unroll
        for (int k = 0; k < 4; ++k) {
            int c = col[e + k];
            ss[k] = sbuf[e + k];
            uu[k] = Xb2[((u32)c << 6) + l];
        }
#pragma unroll
        for (int k = 0; k < 4; ++k) {
            ds += ss[k];
            p0 += ss[k] * __uint_as_float(uu[k] << 16);
            p1 += ss[k] * __uint_as_float(uu[k] & 0xffff0000u);
        }
        e += 4;
    }
    {
        int rem = e1 - e;                        // 0..3, wave-uniform
        if (rem > 0) {
            float sa = sbuf[e];
            u32   ua = Xb2[((u32)col[e] << 6) + l];
            float sb = 0.f; u32 ub = 0;
            float sc2 = 0.f; u32 uc = 0;
            if (rem > 1) { sb  = sbuf[e + 1]; ub = Xb2[((u32)col[e + 1] << 6) + l]; }
            if (rem > 2) { sc2 = sbuf[e + 2]; uc = Xb2[((u32)col[e + 2] << 6) + l]; }
            ds += sa + sb + sc2;
            p0 += sa * __uint_as_float(ua << 16);
            p1 += sa * __uint_as_float(ua & 0xffff0000u);
            p0 += sb * __uint_as_float(ub << 16);
            p1 += sb * __uint_as_float(ub & 0xffff0000u);
            p0 += sc2 * __uint_as_float(uc << 16);
            p1 += sc2 * __uint_as_float(uc & 0xffff0000u);
        }
    }
    float sc = 1.f / (ds + 1e-15f);
    aggb2[((u32)n << 6) + l] = pack2(p0 * sc, p1 * sc);
}

// ---- fused (X@wres + agg@wx + biases) -> wo (+relu?) [+ next-layer ar/ac] --
// 4 waves/block; single 32KB LDS weight buffer, T14 issue-early/write-late:
// next chunk's global loads are issued BEFORE the current GEMM.
template<bool RELU, bool ARAC>
__global__ __launch_bounds__(256) void gtm_fused16(
    const u16* __restrict__ Xb, const u16* __restrict__ aggb,
    const u16* __restrict__ wres, const float* __restrict__ bres,
    const u16* __restrict__ wx, const float* __restrict__ bx,
    const u16* __restrict__ wo, const float* __restrict__ bo,
    const u16* __restrict__ wrc_next, float* __restrict__ ar,
    float* __restrict__ ac, u16* __restrict__ hb, int N)
{
    __shared__ u16 wsh[16384];                         // 32KB staged weights
    __shared__ u16 ylds4[4][16 * D];                   // 4x4KB, wave-private
    const int t = threadIdx.x;
    const int w = t >> 6, l = t & 63, l16 = l & 15, lg = l >> 4;
    u16* ylds = ylds4[w];
    const long r0 = (long)blockIdx.x * 64 + w * 16;
    const long ia = r0 + l16;

    bfrag wreg[8];
    ldw8(wreg, wres, t);                               // wres loads first

    // per-wave A fragments (x rows + agg rows)
    bfrag xa[4], ga[4];
#pragma unroll
    for (int ks = 0; ks < 4; ++ks) {
        if (ia < N) {
            xa[ks] = *(const bfrag*)(Xb   + ia * D + ks * 32 + lg * 8);
            ga[ks] = *(const bfrag*)(aggb + ia * D + ks * 32 + lg * 8);
        } else { xa[ks] = bzero(); ga[ks] = bzero(); }
    }

    facc acc[8];
#pragma unroll
    for (int ct = 0; ct < 8; ++ct) acc[ct] = (facc){0, 0, 0, 0};

    // ---- phase 1: wres
    stw8(wsh, wreg, t);
    __syncthreads();
    ldw8(wreg, wx, t);                                 // prefetch wx under GEMM1
#pragma unroll
    for (int ks = 0; ks < 4; ++ks)
#pragma unroll
        for (int ct = 0; ct < 8; ++ct) {
            bfrag b = *(const bfrag*)(wsh + (((ct * 4 + ks) * 64 + l) << 3));
            acc[ct] = __builtin_amdgcn_mfma_f32_16x16x32_bf16(xa[ks], b, acc[ct], 0, 0, 0);
        }
    __syncthreads();                                   // all reads of wres done

    // ---- phase 2: wx (accumulate into same acc)
    stw8(wsh, wreg, t);
    __syncthreads();
    ldw8(wreg, wo, t);                                 // prefetch wo under GEMM2
#pragma unroll
    for (int ks = 0; ks < 4; ++ks)
#pragma unroll
        for (int ct = 0; ct < 8; ++ct) {
            bfrag b = *(const bfrag*)(wsh + (((ct * 4 + ks) * 64 + l) << 3));
            acc[ct] = __builtin_amdgcn_mfma_f32_16x16x32_bf16(ga[ks], b, acc[ct], 0, 0, 0);
        }
    __syncthreads();                                   // all reads of wx done

    // ---- phase 3: write wo; meanwhile park y in wave-private ylds
    stw8(wsh, wreg, t);
#pragma unroll
    for (int ct = 0; ct < 8; ++ct) {
        int col = ct * 16 + l16;
        float bsum = bres[col] + bx[col];
#pragma unroll
        for (int j = 0; j < 4; ++j)
            st_swz(ylds, lg * 4 + j, col, 256, acc[ct][j] + bsum);
    }
    __syncthreads();                                   // wo staged + ylds written

#pragma unroll
    for (int ct = 0; ct < 8; ++ct) acc[ct] = (facc){0, 0, 0, 0};
#pragma unroll
    for (int ks = 0; ks < 4; ++ks) {
        bfrag a = afrag16(ylds, l16, ks * 32 + lg * 8);
#pragma unroll
        for (int ct = 0; ct < 8; ++ct) {
            bfrag b = *(const bfrag*)(wsh + (((ct * 4 + ks) * 64 + l) << 3));
            acc[ct] = __builtin_amdgcn_mfma_f32_16x16x32_bf16(a, b, acc[ct], 0, 0, 0);
        }
    }
    asm volatile("s_waitcnt lgkmcnt(0)" ::: "memory");   // drain ylds reads before
    __builtin_amdgcn_sched_barrier(0);                   // overwrite (ARAC path)
#pragma unroll
    for (int ct = 0; ct < 8; ++ct) {
        int col = ct * 16 + l16;
        float bov = bo[col];
#pragma unroll
        for (int j = 0; j < 4; ++j) {
            long i = r0 + lg * 4 + j;
            float y = acc[ct][j] + bov;
            if (RELU) y = fmaxf(y, 0.f);
            if (i < N) hb[i * D + col] = f2bf(y);
            if (ARAC) st_swz(ylds, lg * 4 + j, col, 256, y);   // park h for wrc
        }
    }
    if (ARAC) {
        // next layer's ar/ac = h @ wrc^T, using h just parked in LDS
        asm volatile("s_waitcnt lgkmcnt(0)" ::: "memory");
        __builtin_amdgcn_sched_barrier(0);
        facc pr = (facc){0, 0, 0, 0};
#pragma unroll
        for (int ks = 0; ks < 4; ++ks) {
            bfrag b = *(const bfrag*)(wrc_next + ((ks * 64 + l) << 3));
            bfrag a = afrag16(ylds, l16, ks * 32 + lg * 8);
            pr = __builtin_amdgcn_mfma_f32_16x16x32_bf16(a, b, pr, 0, 0, 0);
        }
#pragma unroll
        for (int j = 0; j < 4; ++j) {
            long i = r0 + lg * 4 + j;
            if (i < N) {
                if (l16 < 8) ar[i * DA + l16] = pr[j];
                else         ac[i * DA + (l16 - 8)] = pr[j];
            }
        }
    }
}

// --------------------------------------------------------------- MLP tail ---
// 4 waves/block; w0/w1 in 2x36KB chunks, f0w 24KB — all issue-early/write-late.
__device__ inline void ln_relu_to_lds(facc acc[12], const float* __restrict__ bb,
                                      const float* __restrict__ g,
                                      const float* __restrict__ bln,
                                      int l16, int lg, u16* wz)
{
    float s1[4] = {0, 0, 0, 0}, s2[4] = {0, 0, 0, 0};
#pragma unroll
    for (int ct = 0; ct < 12; ++ct) {
        float bbv = bb[ct * 16 + l16];
#pragma unroll
        for (int j = 0; j < 4; ++j) {
            float xv = acc[ct][j] + bbv;
            acc[ct][j] = xv;
            s1[j] += xv; s2[j] += xv * xv;
        }
    }
#pragma unroll
    for (int j = 0; j < 4; ++j) {
#pragma unroll
        for (int off = 1; off < 16; off <<= 1) {
            s1[j] += __shfl_xor(s1[j], off);
            s2[j] += __shfl_xor(s2[j], off);
        }
    }
#pragma unroll
    for (int ct = 0; ct < 12; ++ct) {
        int cc = ct * 16 + l16;
        float gv = g[cc], bv = bln[cc];
#pragma unroll
        for (int j = 0; j < 4; ++j) {
            float mu  = s1[j] * (1.f / 192.f);
            float var = s2[j] * (1.f / 192.f) - mu * mu;
            float y = (acc[ct][j] - mu) * rsqrtf(var + 1e-5f) * gv + bv;
            y = fmaxf(y, 0.f);
            st_swz(wz, lg * 4 + j, cc, 384, y);
        }
    }
    asm volatile("s_waitcnt lgkmcnt(0)" ::: "memory");
    __builtin_amdgcn_sched_barrier(0);
}

__global__ __launch_bounds__(256) void mlp_tail4(
    const u16* __restrict__ hb,
    const int* __restrict__ src, const int* __restrict__ dst,
    const int* __restrict__ ebh, const u16* __restrict__ embb,
    const u16* __restrict__ w0, const float* __restrict__ b0,
    const u16* __restrict__ w1, const float* __restrict__ b1,
    const float* __restrict__ g, const float* __restrict__ bln,
    const u16* __restrict__ f0w, const float* __restrict__ f0b,
    const float* __restrict__ f1w, const float* __restrict__ f1b,
    float* __restrict__ out, int B)
{
    __shared__ u16 wst[18432];                         // 36KB staging (6-ct chunk)
    __shared__ u16 zs[4][16 * DMH];                    // 4x6KB wave-private
    const int t = threadIdx.x;
    const int w = t >> 6, l = t & 63, l16 = l & 15, lg = l >> 4;
    u16* wz = zs[w];
    const long r0 = (long)blockIdx.x * 64 + w * 16;
    const long ri = r0 + l16;

    bfrag wreg[9];
    ldw9(wreg, w0, t);                                 // chunk L0c0 loads first

    // ---- z fragments built directly in registers
    bfrag za[6];
    if (ri < B) {
        int si = src[ri], di = dst[ri], hi2 = ebh[ri];
#pragma unroll
        for (int ks = 0; ks < 4; ++ks) {
            bfrag hs = *(const bfrag*)(hb + (size_t)si * D + ks * 32 + lg * 8);
            bfrag hd = *(const bfrag*)(hb + (size_t)di * D + ks * 32 + lg * 8);
            bfrag r;
#pragma unroll
            for (int k = 0; k < 8; ++k)
                r[k] = (short)f2bf(bf2f((u16)hs[k]) * bf2f((u16)hd[k]));
            za[ks] = r;
        }
        za[4] = *(const bfrag*)(embb + (size_t)hi2 * DE + lg * 8);
        za[5] = *(const bfrag*)(embb + (size_t)hi2 * DE + 32 + lg * 8);
    } else {
#pragma unroll
        for (int ks = 0; ks < 6; ++ks) za[ks] = bzero();
    }

    facc acc[12];
    // ---- layer 0: A from registers, W in 2 chunks (issue-early/write-late)
#pragma unroll
    for (int ct = 0; ct < 12; ++ct) acc[ct] = (facc){0, 0, 0, 0};
    stw9(wst, wreg, t);
    __syncthreads();
    ldw9(wreg, w0 + 18432, t);                         // prefetch L0c1
#pragma unroll
    for (int ks = 0; ks < 6; ++ks)
#pragma unroll
        for (int ctl = 0; ctl < 6; ++ctl) {
            bfrag b = *(const bfrag*)(wst + (((ctl * 6 + ks) * 64 + l) << 3));
            acc[ctl] = __builtin_amdgcn_mfma_f32_16x16x32_bf16(za[ks], b, acc[ctl], 0, 0, 0);
        }
    __syncthreads();
    stw9(wst, wreg, t);
    __syncthreads();
    ldw9(wreg, w1, t);                                 // prefetch L1c0
#pragma unroll
    for (int ks = 0; ks < 6; ++ks)
#pragma unroll
        for (int ctl = 0; ctl < 6; ++ctl) {
            bfrag b = *(const bfrag*)(wst + (((ctl * 6 + ks) * 64 + l) << 3));
            acc[6 + ctl] = __builtin_amdgcn_mfma_f32_16x16x32_bf16(za[ks], b, acc[6 + ctl], 0, 0, 0);
        }
    ln_relu_to_lds(acc, b0, g, bln, l16, lg, wz);
    __syncthreads();                                   // wst reads done

    // ---- layer 1: A from LDS z, W in 2 chunks
#pragma unroll
    for (int ct = 0; ct < 12; ++ct) acc[ct] = (facc){0, 0, 0, 0};
    stw9(wst, wreg, t);
    __syncthreads();
    ldw9(wreg, w1 + 18432, t);                         // prefetch L1c1
#pragma unroll
    for (int ks = 0; ks < 6; ++ks) {
        bfrag a = zfrag16(wz, l16, ks * 32 + lg * 8);
#pragma unroll
        for (int ctl = 0; ctl < 6; ++ctl) {
            bfrag b = *(const bfrag*)(wst + (((ctl * 6 + ks) * 64 + l) << 3));
            acc[ctl] = __builtin_amdgcn_mfma_f32_16x16x32_bf16(a, b, acc[ctl], 0, 0, 0);
        }
    }
    __syncthreads();
    stw9(wst, wreg, t);
    __syncthreads();
    {
        bfrag f6[6];                                   // prefetch f0w (24KB)
#pragma unroll
        for (int i = 0; i < 6; ++i)
            f6[i] = *(const bfrag*)(f0w + ((i * 256 + t) << 3));
#pragma unroll
        for (int ks = 0; ks < 6; ++ks) {
            bfrag a = zfrag16(wz, l16, ks * 32 + lg * 8);
#pragma unroll
            for (int ctl = 0; ctl < 6; ++ctl) {
                bfrag b = *(const bfrag*)(wst + (((ctl * 6 + ks) * 64 + l) << 3));
                acc[6 + ctl] = __builtin_amdgcn_mfma_f32_16x16x32_bf16(a, b, acc[6 + ctl], 0, 0, 0);
            }
        }
        ln_relu_to_lds(acc, b1, g, bln, l16, lg, wz);
        __syncthreads();                               // wst reads done
#pragma unroll
        for (int i = 0; i < 6; ++i)
            *(bfrag*)(wst + ((i * 256 + t) << 3)) = f6[i];
    }
    __syncthreads();

    // ---- f0 (192->64), f1 (64->1), sigmoid
    facc o[4];
#pragma unroll
    for (int ct = 0; ct < 4; ++ct) o[ct] = (facc){0, 0, 0, 0};
#pragma unroll
    for (int ks = 0; ks < 6; ++ks) {
        bfrag a = zfrag16(wz, l16, ks * 32 + lg * 8);
#pragma unroll
        for (int ct = 0; ct < 4; ++ct) {
            bfrag b = *(const bfrag*)(wst + (((ct * 6 + ks) * 64 + l) << 3));
            o[ct] = __builtin_amdgcn_mfma_f32_16x16x32_bf16(a, b, o[ct], 0, 0, 0);
        }
    }
    float p[4] = {0, 0, 0, 0};
#pragma unroll
    for (int ct = 0; ct < 4; ++ct) {
        int cc = ct * 16 + l16;
        float fb = f0b[cc], fw = f1w[cc];
#pragma unroll
        for (int j = 0; j < 4; ++j) p[j] += (o[ct][j] + fb) * fw;
    }
#pragma unroll
    for (int j = 0; j < 4; ++j) {
#pragma unroll
        for (int off = 1; off < 16; off <<= 1) p[j] += __shfl_xor(p[j], off);
    }
    if (l16 == 0) {
#pragma unroll
        for (int j = 0; j < 4; ++j) {
            long i = r0 + lg * 4 + j;
            if (i < B) out[i] = 1.f / (1.f + expf(-(p[j] + f1b[0])));
        }
    }
}

// ------------------------------------------------------------------ launch --
extern "C" void kernel_launch(void* const* d_in, const int* in_sizes, int n_in,
                              void* d_out, int out_size, void* d_ws, size_t ws_size,
                              hipStream_t stream)
{
    const float* x      = (const float*)d_in[0];
    const int*   row    = (const int*)d_in[1];
    const int*   col    = (const int*)d_in[2];
    const int*   eb_src = (const int*)d_in[3];
    const int*   eb_dst = (const int*)d_in[4];
    const int*   eb_h   = (const int*)d_in[5];
    const float* l_wres[2] = {(const float*)d_in[6],  (const float*)d_in[14]};
    const float* l_bres[2] = {(const float*)d_in[7],  (const float*)d_in[15]};
    const float* l_wr[2]   = {(const float*)d_in[8],  (const float*)d_in[16]};
    const float* l_wc[2]   = {(const float*)d_in[9],  (const float*)d_in[17]};
    const float* l_wx[2]   = {(const float*)d_in[10], (const float*)d_in[18]};
    const float* l_bx[2]   = {(const float*)d_in[11], (const float*)d_in[19]};
    const float* l_wo[2]   = {(const float*)d_in[12], (const float*)d_in[20]};
    const float* l_bo[2]   = {(const float*)d_in[13], (const float*)d_in[21]};
    const float* emb_h  = (const float*)d_in[22];
    const float* mlp0_w = (const float*)d_in[23];
    const float* mlp0_b = (const float*)d_in[24];
    const float* mlp1_w = (const float*)d_in[25];
    const float* mlp1_b = (const float*)d_in[26];
    const float* ln_g   = (const float*)d_in[27];
    const float* ln_b   = (const float*)d_in[28];
    const float* f0_w   = (const float*)d_in[29];
    const float* f0_b   = (const float*)d_in[30];
    const float* f1_w   = (const float*)d_in[31];
    const float* f1_b   = (const float*)d_in[32];

    const int N = in_sizes[0] / D;
    const int E = in_sizes[1];
    const int B = in_sizes[3];

    // workspace layout
    float* arb  = (float*)d_ws;                       // [N,8]
    float* acb  = arb + (size_t)N * DA;               // [N,8]
    float* sbuf = acb + (size_t)N * DA;               // [E]
    int* rowptr = (int*)(sbuf + (size_t)E);           // [N+1]
    uintptr_t bp = (uintptr_t)(rowptr + (N + 1));
    bp = (bp + 15) & ~(uintptr_t)15;
    u16* xb   = (u16*)bp;                             // [N,128] bf16
    u16* h0b  = xb  + (size_t)N * D;                  // [N,128] bf16
    u16* hfb  = h0b + (size_t)N * D;                  // [N,128] bf16
    u16* aggb = hfb + (size_t)N * D;                  // [N,128] bf16
    u16* WB   = aggb + (size_t)N * D;                 // 194880 bf16 weights

    const u16* WRES[2] = {WB + 0,     WB + 49152};
    const u16* WX[2]   = {WB + 16384, WB + 65536};
    const u16* WO[2]   = {WB + 32768, WB + 81920};
    const u16* MW0  = WB + 98304;
    const u16* MW1  = WB + 135168;
    const u16* F0W  = WB + 172032;
    const u16* WRC[2] = {WB + 184320, WB + 186368};
    const u16* EMBB = WB + 188416;

    PrepSrc ps;
    ps.p[0] = l_wres[0]; ps.p[1] = l_wx[0]; ps.p[2] = l_wo[0];
    ps.p[3] = l_wres[1]; ps.p[4] = l_wx[1]; ps.p[5] = l_wo[1];
    ps.p[6] = mlp0_w;    ps.p[7] = mlp1_w;  ps.p[8] = f0_w;
    ps.p[9] = l_wr[0];   ps.p[10] = l_wc[0];
    ps.p[11] = l_wr[1];  ps.p[12] = l_wc[1];
    ps.p[13] = emb_h;

    const int nb64  = (N + 63) / 64;
    const int nbN4  = (N + 3) / 4;
    const int nbE   = (E + 255) / 256;
    const int nbB64 = (B + 63) / 64;
    const long n8   = (long)N * D / 8;
    const long T    = 194880 + n8 + (long)E;
    const int nbT   = (int)((T + 255) / 256);

    prep_all<<<nbT, 256, 0, stream>>>(ps, WB, x, xb, n8, row, rowptr, E, N);
    calc_arac<<<nb64, 256, 0, stream>>>(xb, WRC[0], arb, acb, N);

    // ---- layer 0 (produces h0b and next-layer ar/ac via ARAC epilogue)
    edge_score<<<nbE, 256, 0, stream>>>(row, col, arb, acb, sbuf, E);
    aggregate_b<<<nbN4, 256, 0, stream>>>(rowptr, col, sbuf,
                                          (const u32*)xb, (u32*)aggb, N);
    gtm_fused16<true, true><<<nb64, 256, 0, stream>>>(
        xb, aggb, WRES[0], l_bres[0], WX[0], l_bx[0],
        WO[0], l_bo[0], WRC[1], arb, acb, h0b, N);

    // ---- layer 1
    edge_score<<<nbE, 256, 0, stream>>>(row, col, arb, acb, sbuf, E);
    aggregate_b<<<nbN4, 256, 0, stream>>>(rowptr, col, sbuf,
                                          (const u32*)h0b, (u32*)aggb, N);
    gtm_fused16<false, false><<<nb64, 256, 0, stream>>>(
        h0b, aggb, WRES[1], l_bres[1], WX[1], l_bx[1],
        WO[1], l_bo[1], nullptr, nullptr, nullptr, hfb, N);

    mlp_tail4<<<nbB64, 256, 0, stream>>>(
        hfb, eb_src, eb_dst, eb_h, EMBB,
        MW0, mlp0_b, MW1, mlp1_b, ln_g, ln_b,
        F0W, f0_b, f1_w, f1_b, (float*)d_out, B);
}

// Round 14
// 239.185 us; speedup vs baseline: 1.0228x; 1.0228x over previous
//
#include <hip/hip_runtime.h>
#include <math.h>

#define D   128
#define DA  8
#define DE  64
#define DMH 192

typedef unsigned short u16;
typedef unsigned int   u32;
typedef __attribute__((ext_vector_type(8))) short bfrag;   // 8 bf16 = 4 VGPRs
typedef __attribute__((ext_vector_type(4))) float facc;    // MFMA C/D

__device__ inline u16 f2bf(float v) {
    unsigned u = __float_as_uint(v);
    return (u16)((u + 0x7fffu + ((u >> 16) & 1u)) >> 16);   // RNE
}
__device__ inline float bf2f(u16 v) { return __uint_as_float((u32)v << 16); }
__device__ inline u32 pack2(float a, float b) {
    return (u32)f2bf(a) | ((u32)f2bf(b) << 16);
}
__device__ inline bfrag bzero() {
    bfrag r;
#pragma unroll
    for (int i = 0; i < 8; ++i) r[i] = 0;
    return r;
}
// swizzled LDS fragment readers (row-XOR banks)
__device__ inline bfrag afrag16(const u16* wlds, int row, int kb) {   // stride 256B
    int off = row * 256 + (((kb >> 3) * 16) ^ ((row & 7) << 4));
    return *(const bfrag*)((const char*)wlds + off);
}
__device__ inline bfrag zfrag16(const u16* wlds, int row, int kb) {   // stride 384B
    int off = row * 384 + (((kb >> 3) * 16) ^ ((row & 7) << 4));
    return *(const bfrag*)((const char*)wlds + off);
}
__device__ inline void st_swz(u16* wlds, int row, int col, int stride, float v) {
    *(u16*)((char*)wlds + row * stride
            + ((((col >> 3) * 16) ^ ((row & 7) << 4)) + (col & 7) * 2)) = f2bf(v);
}
// cooperative 32KB weight stage: 256 threads x 8 x 16B (reg-staged, linear)
__device__ inline void stage32k(u16* __restrict__ dst, const u16* __restrict__ src,
                                int t) {
    bfrag tmp[8];
#pragma unroll
    for (int i = 0; i < 8; ++i)
        tmp[i] = *(const bfrag*)(src + (size_t)((i << 8) + t) * 8);
#pragma unroll
    for (int i = 0; i < 8; ++i)
        *(bfrag*)(dst + ((i << 8) + t) * 8) = tmp[i];
}

// --------------------------------------------------------------- prep_all ---
// 1) weights -> bf16, repacked fragment-major: dst[((tct*nks+ks)*64+lane)*8+m]
//    = W[tct*16+(lane&15)][ks*32+(lane>>4)*8+m]  (emb stays row-major bf16)
// 2) x -> bf16   3) rowptr build
struct PrepSrc { const float* p[14]; };
__global__ __launch_bounds__(256) void prep_all(
    PrepSrc ps, u16* __restrict__ wb,
    const float* __restrict__ x, u16* __restrict__ xb, long n8,
    const int* __restrict__ row, int* __restrict__ rowptr, int E, int N)
{
    long task = (long)blockIdx.x * 256 + threadIdx.x;
    if (task < 194880) {
        int idx = (int)task;
        const int roff[13] = {0, 16384, 32768, 49152, 65536, 81920, 98304,
                              135168, 172032, 184320, 186368, 188416, 194880};
        int r = 0;
#pragma unroll
        for (int k = 1; k < 12; ++k) if (idx >= roff[k]) r = k;
        int local = idx - roff[r];
        float v;
        if (r == 11) {
            v = ps.p[13][local];                       // emb, plain
        } else {
            int K   = (r >= 6 && r <= 8) ? DMH : D;
            int nks = K >> 5;
            int m = local & 7, lane = (local >> 3) & 63;
            int l16 = lane & 15, lg = lane >> 4;
            int rest = local >> 9;
            int ks = rest % nks, tct = rest / nks;
            int rrow = tct * 16 + l16;
            int k = ks * 32 + lg * 8 + m;
            if (r == 9)       v = (rrow < 8) ? ps.p[9][rrow * D + k]
                                             : ps.p[10][(rrow - 8) * D + k];
            else if (r == 10) v = (rrow < 8) ? ps.p[11][rrow * D + k]
                                             : ps.p[12][(rrow - 8) * D + k];
            else              v = ps.p[r][(size_t)rrow * K + k];
        }
        wb[idx] = f2bf(v);
        return;
    }
    task -= 194880;
    if (task < n8) {                                    // x -> bf16
        long i = task;
        __align__(16) float buf[8];
        const float4* p = (const float4*)(x + i * 8);
        ((float4*)buf)[0] = p[0];
        ((float4*)buf)[1] = p[1];
        bfrag o;
#pragma unroll
        for (int k = 0; k < 8; ++k) o[k] = (short)f2bf(buf[k]);
        *(bfrag*)(xb + i * 8) = o;
        return;
    }
    task -= n8;
    if (task < E) {                                     // rowptr
        int e = (int)task;
        int cur  = row[e];
        int prev = (e == 0) ? -1 : row[e - 1];
        for (int r2 = prev + 1; r2 <= cur; ++r2) rowptr[r2] = e;
        if (e == E - 1)
            for (int r2 = cur + 1; r2 <= N; ++r2) rowptr[r2] = E;
    }
}

// --------------------------------------------------- ar/ac projection (L0) --
// 4 independent waves per 256-thread block
__global__ __launch_bounds__(256) void calc_arac(
    const u16* __restrict__ Xb, const u16* __restrict__ wrc,
    float* __restrict__ ar, float* __restrict__ ac, int N)
{
    const int t = threadIdx.x;
    const int w = t >> 6, l = t & 63, l16 = l & 15, lg = l >> 4;
    const long r0 = (long)blockIdx.x * 64 + w * 16;
    const long ia = r0 + l16;
    bfrag a[4];
#pragma unroll
    for (int ks = 0; ks < 4; ++ks)
        a[ks] = (ia < N) ? *(const bfrag*)(Xb + ia * D + ks * 32 + lg * 8) : bzero();
    facc acc = (facc){0, 0, 0, 0};
#pragma unroll
    for (int ks = 0; ks < 4; ++ks) {
        bfrag b = *(const bfrag*)(wrc + ((ks * 64 + l) << 3));
        acc = __builtin_amdgcn_mfma_f32_16x16x32_bf16(a[ks], b, acc, 0, 0, 0);
    }
#pragma unroll
    for (int j = 0; j < 4; ++j) {
        long i = r0 + lg * 4 + j;
        if (i < N) {
            if (l16 < 8) ar[i * DA + l16] = acc[j];
            else         ac[i * DA + (l16 - 8)] = acc[j];
        }
    }
}

// -------------------------------------------------------------- edge s ------
__global__ void edge_score(const int* __restrict__ row, const int* __restrict__ col,
                           const float* __restrict__ ar, const float* __restrict__ ac,
                           float* __restrict__ sbuf, int E)
{
    int e = blockIdx.x * 256 + threadIdx.x;
    if (e >= E) return;
    int r = row[e], c = col[e];
    float4 a0 = *(const float4*)&ar[(long)r * DA];
    float4 a1 = *(const float4*)&ar[(long)r * DA + 4];
    float4 c0 = *(const float4*)&ac[(long)c * DA];
    float4 c1 = *(const float4*)&ac[(long)c * DA + 4];
    float s = a0.x * c0.x + a0.y * c0.y + a0.z * c0.z + a0.w * c0.w
            + a1.x * c1.x + a1.y * c1.y + a1.z * c1.z + a1.w * c1.w;
    s *= 0.35355339059327373f;           // 1/sqrt(8)
    s = (s >= 0.f) ? s : 0.2f * s;       // leaky relu
    sbuf[e] = expf(s);                   // global-max shift cancels in the row norm
}

// ----------------------------------------------------------- aggregate ------
// 4 independent waves/block, one node per wave; 2 bf16 cols/lane.
// 16-deep gather pipeline + 8 + 4 + predicated 0..3 remainder.
__global__ __launch_bounds__(256) void aggregate_b(
    const int* __restrict__ rowptr, const int* __restrict__ col,
    const float* __restrict__ sbuf, const u32* __restrict__ Xb2,
    u32* __restrict__ aggb2, int N)
{
    const int w = threadIdx.x >> 6, l = threadIdx.x & 63;
    const int n = blockIdx.x * 4 + w;
    if (n >= N) return;
    const int e0 = rowptr[n], e1 = rowptr[n + 1];
    float p0 = 0.f, p1 = 0.f, ds = 0.f;
    int e = e0;
    for (; e + 16 <= e1; e += 16) {
        float ss[16]; u32 uu[16];
#pragma unroll
        for (int k = 0; k < 16; ++k) {
            int c = col[e + k];
            ss[k] = sbuf[e + k];
            uu[k] = Xb2[((u32)c << 6) + l];
        }
#pragma unroll
        for (int k = 0; k < 16; ++k) {
            ds += ss[k];
            p0 += ss[k] * __uint_as_float(uu[k] << 16);
            p1 += ss[k] * __uint_as_float(uu[k] & 0xffff0000u);
        }
    }
    if (e + 8 <= e1) {
        float ss[8]; u32 uu[8];
#pragma unroll
        for (int k = 0; k < 8; ++k) {
            int c = col[e + k];
            ss[k] = sbuf[e + k];
            uu[k] = Xb2[((u32)c << 6) + l];
        }
#pragma unroll
        for (int k = 0; k < 8; ++k) {
            ds += ss[k];
            p0 += ss[k] * __uint_as_float(uu[k] << 16);
            p1 += ss[k] * __uint_as_float(uu[k] & 0xffff0000u);
        }
        e += 8;
    }
    if (e + 4 <= e1) {
        float ss[4]; u32 uu[4];
#pragma unroll
        for (int k = 0; k < 4; ++k) {
            int c = col[e + k];
            ss[k] = sbuf[e + k];
            uu[k] = Xb2[((u32)c << 6) + l];
        }
#pragma unroll
        for (int k = 0; k < 4; ++k) {
            ds += ss[k];
            p0 += ss[k] * __uint_as_float(uu[k] << 16);
            p1 += ss[k] * __uint_as_float(uu[k] & 0xffff0000u);
        }
        e += 4;
    }
    {
        int rem = e1 - e;                        // 0..3, wave-uniform
        if (rem > 0) {
            float sa = sbuf[e];
            u32   ua = Xb2[((u32)col[e] << 6) + l];
            float sb = 0.f; u32 ub = 0;
            float sc2 = 0.f; u32 uc = 0;
            if (rem > 1) { sb  = sbuf[e + 1]; ub = Xb2[((u32)col[e + 1] << 6) + l]; }
            if (rem > 2) { sc2 = sbuf[e + 2]; uc = Xb2[((u32)col[e + 2] << 6) + l]; }
            ds += sa + sb + sc2;
            p0 += sa * __uint_as_float(ua << 16);
            p1 += sa * __uint_as_float(ua & 0xffff0000u);
            p0 += sb * __uint_as_float(ub << 16);
            p1 += sb * __uint_as_float(ub & 0xffff0000u);
            p0 += sc2 * __uint_as_float(uc << 16);
            p1 += sc2 * __uint_as_float(uc & 0xffff0000u);
        }
    }
    float sc = 1.f / (ds + 1e-15f);
    aggb2[((u32)n << 6) + l] = pack2(p0 * sc, p1 * sc);
}

// ---- fused (X@wres + agg@wx + biases) -> wo (+relu?) [+ next-layer ar/ac] --
// 4 waves/block; weights staged in block-shared LDS (32KB region, 3 phases)
template<bool RELU, bool ARAC>
__global__ __launch_bounds__(256) void gtm_fused16(
    const u16* __restrict__ Xb, const u16* __restrict__ aggb,
    const u16* __restrict__ wres, const float* __restrict__ bres,
    const u16* __restrict__ wx, const float* __restrict__ bx,
    const u16* __restrict__ wo, const float* __restrict__ bo,
    const u16* __restrict__ wrc_next, float* __restrict__ ar,
    float* __restrict__ ac, u16* __restrict__ hb, int N)
{
    __shared__ u16 wsh[16384];                         // 32KB staged weights
    __shared__ u16 ylds4[4][16 * D];                   // 4x4KB, wave-private
    const int t = threadIdx.x;
    const int w = t >> 6, l = t & 63, l16 = l & 15, lg = l >> 4;
    u16* ylds = ylds4[w];
    const long r0 = (long)blockIdx.x * 64 + w * 16;
    const long ia = r0 + l16;

    // per-wave A fragments (x rows + agg rows)
    bfrag xa[4], ga[4];
#pragma unroll
    for (int ks = 0; ks < 4; ++ks) {
        if (ia < N) {
            xa[ks] = *(const bfrag*)(Xb   + ia * D + ks * 32 + lg * 8);
            ga[ks] = *(const bfrag*)(aggb + ia * D + ks * 32 + lg * 8);
        } else { xa[ks] = bzero(); ga[ks] = bzero(); }
    }

    facc acc[8];
#pragma unroll
    for (int ct = 0; ct < 8; ++ct) acc[ct] = (facc){0, 0, 0, 0};

    // ---- phase 1: wres
    stage32k(wsh, wres, t);
    __syncthreads();
#pragma unroll
    for (int ks = 0; ks < 4; ++ks)
#pragma unroll
        for (int ct = 0; ct < 8; ++ct) {
            bfrag b = *(const bfrag*)(wsh + (((ct * 4 + ks) * 64 + l) << 3));
            acc[ct] = __builtin_amdgcn_mfma_f32_16x16x32_bf16(xa[ks], b, acc[ct], 0, 0, 0);
        }
    __syncthreads();                                   // all reads of wres done

    // ---- phase 2: wx (accumulate into same acc)
    stage32k(wsh, wx, t);
    __syncthreads();
#pragma unroll
    for (int ks = 0; ks < 4; ++ks)
#pragma unroll
        for (int ct = 0; ct < 8; ++ct) {
            bfrag b = *(const bfrag*)(wsh + (((ct * 4 + ks) * 64 + l) << 3));
            acc[ct] = __builtin_amdgcn_mfma_f32_16x16x32_bf16(ga[ks], b, acc[ct], 0, 0, 0);
        }
    __syncthreads();                                   // all reads of wx done

    // ---- phase 3: stage wo; meanwhile park y in wave-private ylds
    stage32k(wsh, wo, t);
#pragma unroll
    for (int ct = 0; ct < 8; ++ct) {
        int col = ct * 16 + l16;
        float bsum = bres[col] + bx[col];
#pragma unroll
        for (int j = 0; j < 4; ++j)
            st_swz(ylds, lg * 4 + j, col, 256, acc[ct][j] + bsum);
    }
    __syncthreads();                                   // wo staged + ylds written

#pragma unroll
    for (int ct = 0; ct < 8; ++ct) acc[ct] = (facc){0, 0, 0, 0};
#pragma unroll
    for (int ks = 0; ks < 4; ++ks) {
        bfrag a = afrag16(ylds, l16, ks * 32 + lg * 8);
#pragma unroll
        for (int ct = 0; ct < 8; ++ct) {
            bfrag b = *(const bfrag*)(wsh + (((ct * 4 + ks) * 64 + l) << 3));
            acc[ct] = __builtin_amdgcn_mfma_f32_16x16x32_bf16(a, b, acc[ct], 0, 0, 0);
        }
    }
    asm volatile("s_waitcnt lgkmcnt(0)" ::: "memory");   // drain ylds reads before
    __builtin_amdgcn_sched_barrier(0);                   // overwrite (ARAC path)
#pragma unroll
    for (int ct = 0; ct < 8; ++ct) {
        int col = ct * 16 + l16;
        float bov = bo[col];
#pragma unroll
        for (int j = 0; j < 4; ++j) {
            long i = r0 + lg * 4 + j;
            float y = acc[ct][j] + bov;
            if (RELU) y = fmaxf(y, 0.f);
            if (i < N) hb[i * D + col] = f2bf(y);
            if (ARAC) st_swz(ylds, lg * 4 + j, col, 256, y);   // park h for wrc
        }
    }
    if (ARAC) {
        // next layer's ar/ac = h @ wrc^T, using h just parked in LDS
        asm volatile("s_waitcnt lgkmcnt(0)" ::: "memory");
        __builtin_amdgcn_sched_barrier(0);
        facc pr = (facc){0, 0, 0, 0};
#pragma unroll
        for (int ks = 0; ks < 4; ++ks) {
            bfrag b = *(const bfrag*)(wrc_next + ((ks * 64 + l) << 3));
            bfrag a = afrag16(ylds, l16, ks * 32 + lg * 8);
            pr = __builtin_amdgcn_mfma_f32_16x16x32_bf16(a, b, pr, 0, 0, 0);
        }
#pragma unroll
        for (int j = 0; j < 4; ++j) {
            long i = r0 + lg * 4 + j;
            if (i < N) {
                if (l16 < 8) ar[i * DA + l16] = pr[j];
                else         ac[i * DA + (l16 - 8)] = pr[j];
            }
        }
    }
}

// --------------------------------------------------------------- MLP tail ---
// 4 waves/block; w0/w1 staged in 2x36KB chunks, f0w staged once (24KB).
__device__ inline void ln_relu_to_lds(facc acc[12], const float* __restrict__ bb,
                                      const float* __restrict__ g,
                                      const float* __restrict__ bln,
                                      int l16, int lg, u16* wz)
{
    float s1[4] = {0, 0, 0, 0}, s2[4] = {0, 0, 0, 0};
#pragma unroll
    for (int ct = 0; ct < 12; ++ct) {
        float bbv = bb[ct * 16 + l16];
#pragma unroll
        for (int j = 0; j < 4; ++j) {
            float xv = acc[ct][j] + bbv;
            acc[ct][j] = xv;
            s1[j] += xv; s2[j] += xv * xv;
        }
    }
#pragma unroll
    for (int j = 0; j < 4; ++j) {
#pragma unroll
        for (int off = 1; off < 16; off <<= 1) {
            s1[j] += __shfl_xor(s1[j], off);
            s2[j] += __shfl_xor(s2[j], off);
        }
    }
#pragma unroll
    for (int ct = 0; ct < 12; ++ct) {
        int cc = ct * 16 + l16;
        float gv = g[cc], bv = bln[cc];
#pragma unroll
        for (int j = 0; j < 4; ++j) {
            float mu  = s1[j] * (1.f / 192.f);
            float var = s2[j] * (1.f / 192.f) - mu * mu;
            float y = (acc[ct][j] - mu) * rsqrtf(var + 1e-5f) * gv + bv;
            y = fmaxf(y, 0.f);
            st_swz(wz, lg * 4 + j, cc, 384, y);
        }
    }
    asm volatile("s_waitcnt lgkmcnt(0)" ::: "memory");
    __builtin_amdgcn_sched_barrier(0);
}

__global__ __launch_bounds__(256) void mlp_tail4(
    const u16* __restrict__ hb,
    const int* __restrict__ src, const int* __restrict__ dst,
    const int* __restrict__ ebh, const u16* __restrict__ embb,
    const u16* __restrict__ w0, const float* __restrict__ b0,
    const u16* __restrict__ w1, const float* __restrict__ b1,
    const float* __restrict__ g, const float* __restrict__ bln,
    const u16* __restrict__ f0w, const float* __restrict__ f0b,
    const float* __restrict__ f1w, const float* __restrict__ f1b,
    float* __restrict__ out, int B)
{
    __shared__ u16 wst[18432];                         // 36KB staging (6-ct chunk)
    __shared__ u16 zs[4][16 * DMH];                    // 4x6KB wave-private
    const int t = threadIdx.x;
    const int w = t >> 6, l = t & 63, l16 = l & 15, lg = l >> 4;
    u16* wz = zs[w];
    const long r0 = (long)blockIdx.x * 64 + w * 16;
    const long ri = r0 + l16;

    // ---- z fragments built directly in registers
    bfrag za[6];
    if (ri < B) {
        int si = src[ri], di = dst[ri], hi2 = ebh[ri];
#pragma unroll
        for (int ks = 0; ks < 4; ++ks) {
            bfrag hs = *(const bfrag*)(hb + (size_t)si * D + ks * 32 + lg * 8);
            bfrag hd = *(const bfrag*)(hb + (size_t)di * D + ks * 32 + lg * 8);
            bfrag r;
#pragma unroll
            for (int k = 0; k < 8; ++k)
                r[k] = (short)f2bf(bf2f((u16)hs[k]) * bf2f((u16)hd[k]));
            za[ks] = r;
        }
        za[4] = *(const bfrag*)(embb + (size_t)hi2 * DE + lg * 8);
        za[5] = *(const bfrag*)(embb + (size_t)hi2 * DE + 32 + lg * 8);
    } else {
#pragma unroll
        for (int ks = 0; ks < 6; ++ks) za[ks] = bzero();
    }

    facc acc[12];
    // ---- layer 0: A from registers, W staged in 2 chunks of 6 ct
#pragma unroll
    for (int ct = 0; ct < 12; ++ct) acc[ct] = (facc){0, 0, 0, 0};
#pragma unroll
    for (int c = 0; c < 2; ++c) {
        {
            bfrag tmp[9];
#pragma unroll
            for (int i = 0; i < 9; ++i)
                tmp[i] = *(const bfrag*)(w0 + (size_t)c * 18432 + ((i * 256 + t) << 3));
#pragma unroll
            for (int i = 0; i < 9; ++i)
                *(bfrag*)(wst + ((i * 256 + t) << 3)) = tmp[i];
        }
        __syncthreads();
#pragma unroll
        for (int ks = 0; ks < 6; ++ks)
#pragma unroll
            for (int ctl = 0; ctl < 6; ++ctl) {
                bfrag b = *(const bfrag*)(wst + (((ctl * 6 + ks) * 64 + l) << 3));
                acc[c * 6 + ctl] =
                    __builtin_amdgcn_mfma_f32_16x16x32_bf16(za[ks], b, acc[c * 6 + ctl], 0, 0, 0);
            }
        __syncthreads();
    }
    ln_relu_to_lds(acc, b0, g, bln, l16, lg, wz);

    // ---- layer 1: A from LDS z, W staged in 2 chunks
#pragma unroll
    for (int ct = 0; ct < 12; ++ct) acc[ct] = (facc){0, 0, 0, 0};
#pragma unroll
    for (int c = 0; c < 2; ++c) {
        {
            bfrag tmp[9];
#pragma unroll
            for (int i = 0; i < 9; ++i)
                tmp[i] = *(const bfrag*)(w1 + (size_t)c * 18432 + ((i * 256 + t) << 3));
#pragma unroll
            for (int i = 0; i < 9; ++i)
                *(bfrag*)(wst + ((i * 256 + t) << 3)) = tmp[i];
        }
        __syncthreads();
#pragma unroll
        for (int ks = 0; ks < 6; ++ks) {
            bfrag a = zfrag16(wz, l16, ks * 32 + lg * 8);
#pragma unroll
            for (int ctl = 0; ctl < 6; ++ctl) {
                bfrag b = *(const bfrag*)(wst + (((ctl * 6 + ks) * 64 + l) << 3));
                acc[c * 6 + ctl] =
                    __builtin_amdgcn_mfma_f32_16x16x32_bf16(a, b, acc[c * 6 + ctl], 0, 0, 0);
            }
        }
        __syncthreads();
    }
    ln_relu_to_lds(acc, b1, g, bln, l16, lg, wz);

    // ---- f0 (192->64): stage 24KB once
    {
        bfrag tmp[6];
#pragma unroll
        for (int i = 0; i < 6; ++i)
            tmp[i] = *(const bfrag*)(f0w + ((i * 256 + t) << 3));
#pragma unroll
        for (int i = 0; i < 6; ++i)
            *(bfrag*)(wst + ((i * 256 + t) << 3)) = tmp[i];
    }
    __syncthreads();
    facc o[4];
#pragma unroll
    for (int ct = 0; ct < 4; ++ct) o[ct] = (facc){0, 0, 0, 0};
#pragma unroll
    for (int ks = 0; ks < 6; ++ks) {
        bfrag a = zfrag16(wz, l16, ks * 32 + lg * 8);
#pragma unroll
        for (int ct = 0; ct < 4; ++ct) {
            bfrag b = *(const bfrag*)(wst + (((ct * 6 + ks) * 64 + l) << 3));
            o[ct] = __builtin_amdgcn_mfma_f32_16x16x32_bf16(a, b, o[ct], 0, 0, 0);
        }
    }
    float p[4] = {0, 0, 0, 0};
#pragma unroll
    for (int ct = 0; ct < 4; ++ct) {
        int cc = ct * 16 + l16;
        float fb = f0b[cc], fw = f1w[cc];
#pragma unroll
        for (int j = 0; j < 4; ++j) p[j] += (o[ct][j] + fb) * fw;
    }
#pragma unroll
    for (int j = 0; j < 4; ++j) {
#pragma unroll
        for (int off = 1; off < 16; off <<= 1) p[j] += __shfl_xor(p[j], off);
    }
    if (l16 == 0) {
#pragma unroll
        for (int j = 0; j < 4; ++j) {
            long i = r0 + lg * 4 + j;
            if (i < B) out[i] = 1.f / (1.f + expf(-(p[j] + f1b[0])));
        }
    }
}

// ------------------------------------------------------------------ launch --
extern "C" void kernel_launch(void* const* d_in, const int* in_sizes, int n_in,
                              void* d_out, int out_size, void* d_ws, size_t ws_size,
                              hipStream_t stream)
{
    const float* x      = (const float*)d_in[0];
    const int*   row    = (const int*)d_in[1];
    const int*   col    = (const int*)d_in[2];
    const int*   eb_src = (const int*)d_in[3];
    const int*   eb_dst = (const int*)d_in[4];
    const int*   eb_h   = (const int*)d_in[5];
    const float* l_wres[2] = {(const float*)d_in[6],  (const float*)d_in[14]};
    const float* l_bres[2] = {(const float*)d_in[7],  (const float*)d_in[15]};
    const float* l_wr[2]   = {(const float*)d_in[8],  (const float*)d_in[16]};
    const float* l_wc[2]   = {(const float*)d_in[9],  (const float*)d_in[17]};
    const float* l_wx[2]   = {(const float*)d_in[10], (const float*)d_in[18]};
    const float* l_bx[2]   = {(const float*)d_in[11], (const float*)d_in[19]};
    const float* l_wo[2]   = {(const float*)d_in[12], (const float*)d_in[20]};
    const float* l_bo[2]   = {(const float*)d_in[13], (const float*)d_in[21]};
    const float* emb_h  = (const float*)d_in[22];
    const float* mlp0_w = (const float*)d_in[23];
    const float* mlp0_b = (const float*)d_in[24];
    const float* mlp1_w = (const float*)d_in[25];
    const float* mlp1_b = (const float*)d_in[26];
    const float* ln_g   = (const float*)d_in[27];
    const float* ln_b   = (const float*)d_in[28];
    const float* f0_w   = (const float*)d_in[29];
    const float* f0_b   = (const float*)d_in[30];
    const float* f1_w   = (const float*)d_in[31];
    const float* f1_b   = (const float*)d_in[32];

    const int N = in_sizes[0] / D;
    const int E = in_sizes[1];
    const int B = in_sizes[3];

    // workspace layout
    float* arb  = (float*)d_ws;                       // [N,8]
    float* acb  = arb + (size_t)N * DA;               // [N,8]
    float* sbuf = acb + (size_t)N * DA;               // [E]
    int* rowptr = (int*)(sbuf + (size_t)E);           // [N+1]
    uintptr_t bp = (uintptr_t)(rowptr + (N + 1));
    bp = (bp + 15) & ~(uintptr_t)15;
    u16* xb   = (u16*)bp;                             // [N,128] bf16
    u16* h0b  = xb  + (size_t)N * D;                  // [N,128] bf16
    u16* hfb  = h0b + (size_t)N * D;                  // [N,128] bf16
    u16* aggb = hfb + (size_t)N * D;                  // [N,128] bf16
    u16* WB   = aggb + (size_t)N * D;                 // 194880 bf16 weights

    const u16* WRES[2] = {WB + 0,     WB + 49152};
    const u16* WX[2]   = {WB + 16384, WB + 65536};
    const u16* WO[2]   = {WB + 32768, WB + 81920};
    const u16* MW0  = WB + 98304;
    const u16* MW1  = WB + 135168;
    const u16* F0W  = WB + 172032;
    const u16* WRC[2] = {WB + 184320, WB + 186368};
    const u16* EMBB = WB + 188416;

    PrepSrc ps;
    ps.p[0] = l_wres[0]; ps.p[1] = l_wx[0]; ps.p[2] = l_wo[0];
    ps.p[3] = l_wres[1]; ps.p[4] = l_wx[1]; ps.p[5] = l_wo[1];
    ps.p[6] = mlp0_w;    ps.p[7] = mlp1_w;  ps.p[8] = f0_w;
    ps.p[9] = l_wr[0];   ps.p[10] = l_wc[0];
    ps.p[11] = l_wr[1];  ps.p[12] = l_wc[1];
    ps.p[13] = emb_h;

    const int nb64  = (N + 63) / 64;
    const int nbN4  = (N + 3) / 4;
    const int nbE   = (E + 255) / 256;
    const int nbB64 = (B + 63) / 64;
    const long n8   = (long)N * D / 8;
    const long T    = 194880 + n8 + (long)E;
    const int nbT   = (int)((T + 255) / 256);

    prep_all<<<nbT, 256, 0, stream>>>(ps, WB, x, xb, n8, row, rowptr, E, N);
    calc_arac<<<nb64, 256, 0, stream>>>(xb, WRC[0], arb, acb, N);

    // ---- layer 0 (produces h0b and next-layer ar/ac via ARAC epilogue)
    edge_score<<<nbE, 256, 0, stream>>>(row, col, arb, acb, sbuf, E);
    aggregate_b<<<nbN4, 256, 0, stream>>>(rowptr, col, sbuf,
                                          (const u32*)xb, (u32*)aggb, N);
    gtm_fused16<true, true><<<nb64, 256, 0, stream>>>(
        xb, aggb, WRES[0], l_bres[0], WX[0], l_bx[0],
        WO[0], l_bo[0], WRC[1], arb, acb, h0b, N);

    // ---- layer 1
    edge_score<<<nbE, 256, 0, stream>>>(row, col, arb, acb, sbuf, E);
    aggregate_b<<<nbN4, 256, 0, stream>>>(rowptr, col, sbuf,
                                          (const u32*)h0b, (u32*)aggb, N);
    gtm_fused16<false, false><<<nb64, 256, 0, stream>>>(
        h0b, aggb, WRES[1], l_bres[1], WX[1], l_bx[1],
        WO[1], l_bo[1], nullptr, nullptr, nullptr, hfb, N);

    mlp_tail4<<<nbB64, 256, 0, stream>>>(
        hfb, eb_src, eb_dst, eb_h, EMBB,
        MW0, mlp0_b, MW1, mlp1_b, ln_g, ln_b,
        F0W, f0_b, f1_w, f1_b, (float*)d_out, B);
}